// Round 2
// baseline (630.776 us; speedup 1.0000x reference)
//
#include <hip/hip_runtime.h>

// Upscale2d: x [8,64,256,256] f32 -> out [8,64,512,512] f32.
// Zero-insert upsample x2 + FIR outer([1,3,3,1]) reduces to separable
// 2-tap polyphase:  out[2i]   = (x[i-1] + 3 x[i]) / 4
//                   out[2i+1] = (3 x[i] + x[i+1]) / 4   (zero pad at edges)
// applied in y then x (combined scale 1/16).

#define H_IN 256
#define W_IN 256
#define NC   512        // N*C = 8*64 planes

typedef float f32x4 __attribute__((ext_vector_type(4)));

__global__ __launch_bounds__(256) void Upscale2d_kernel(
    const float* __restrict__ x, float* __restrict__ out)
{
    // One thread -> 8 output cols of one output row.
    // 64 threads (one wave) -> one full 512-wide output row.
    const int g  = blockIdx.x * 256 + threadIdx.x;
    const int t  = g & 63;           // column group: out cols 8t..8t+7
    const int oy = (g >> 6) & 511;   // output row (H2=512)
    const int p  = g >> 15;          // plane index (n*c)

    const float* xp = x + (size_t)p * (H_IN * W_IN);

    const int i  = oy >> 1;
    const int py = oy & 1;
    // rows contributing to this output row and their weights
    const int   r0  = i - 1 + py;        // py=0: i-1 ; py=1: i
    const int   r1  = r0 + 1;
    const float wy0 = py ? 3.0f : 1.0f;
    const float wy1 = py ? 1.0f : 3.0f;

    const int c0 = t << 2;               // input cols c0..c0+3 (+ c0-1, c0+4)

    // load 6 input values of a row (cols c0-1 .. c0+4), zero outside
    float a[6], b[6];
    {
        if (r0 >= 0) {  // r0 < H_IN always (max i = 255 -> r0 <= 255)
            const float* row = xp + (size_t)r0 * W_IN;
            const f32x4 m = *reinterpret_cast<const f32x4*>(row + c0);
            a[1] = m.x; a[2] = m.y; a[3] = m.z; a[4] = m.w;
            a[0] = (c0 > 0)          ? row[c0 - 1] : 0.0f;
            a[5] = (c0 + 4 < W_IN)   ? row[c0 + 4] : 0.0f;
        } else {
            #pragma unroll
            for (int k = 0; k < 6; ++k) a[k] = 0.0f;
        }
        if (r1 < H_IN) { // r1 >= 0 always
            const float* row = xp + (size_t)r1 * W_IN;
            const f32x4 m = *reinterpret_cast<const f32x4*>(row + c0);
            b[1] = m.x; b[2] = m.y; b[3] = m.z; b[4] = m.w;
            b[0] = (c0 > 0)          ? row[c0 - 1] : 0.0f;
            b[5] = (c0 + 4 < W_IN)   ? row[c0 + 4] : 0.0f;
        } else {
            #pragma unroll
            for (int k = 0; k < 6; ++k) b[k] = 0.0f;
        }
    }

    // combine rows (separable y pass), weights raw {1,3}
    float u[6];
    #pragma unroll
    for (int k = 0; k < 6; ++k) u[k] = wy0 * a[k] + wy1 * b[k];

    // x pass: even col 2j -> u(j-1) + 3 u(j); odd col 2j+1 -> 3 u(j) + u(j+1)
    // local index of input col (c0-1+q) is q; j runs c0..c0+3 -> local 1..4
    const float s = 1.0f / 16.0f;
    float o[8];
    #pragma unroll
    for (int q = 0; q < 4; ++q) {
        const float ujm = u[q];
        const float uj  = u[q + 1];
        const float ujp = u[q + 2];
        o[2 * q]     = (ujm + 3.0f * uj) * s;
        o[2 * q + 1] = (3.0f * uj + ujp) * s;
    }

    // store 8 contiguous floats: 2x float4, nontemporal (write-once stream)
    float* orow = out + (((size_t)((p << 9) + oy)) << 9) + (t << 3);
    f32x4 v0; v0.x = o[0]; v0.y = o[1]; v0.z = o[2]; v0.w = o[3];
    f32x4 v1; v1.x = o[4]; v1.y = o[5]; v1.z = o[6]; v1.w = o[7];
    __builtin_nontemporal_store(v0, reinterpret_cast<f32x4*>(orow));
    __builtin_nontemporal_store(v1, reinterpret_cast<f32x4*>(orow) + 1);
}

extern "C" void kernel_launch(void* const* d_in, const int* in_sizes, int n_in,
                              void* d_out, int out_size, void* d_ws, size_t ws_size,
                              hipStream_t stream) {
    const float* x = (const float*)d_in[0];
    float* out = (float*)d_out;
    // total threads = NC * H2 * (W2/8) = 512 * 512 * 64 = 2^24
    const int total = NC * 512 * 64;
    const int block = 256;
    const int grid  = total / block;   // 65536
    Upscale2d_kernel<<<grid, block, 0, stream>>>(x, out);
}